// Round 8
// baseline (264.293 us; speedup 1.0000x reference)
//
#include <hip/hip_runtime.h>

#define HW 36864            // 192*192
#define HDIM 192
#define NUNITS 8192         // 1024 windows * 8 heads
#define UPB 2               // units (waves) per block
#define UDW 2688            // LDS dwords per unit
#define QO 0                // qbuf: 64 rows * 12 dw (24 f16)
#define KO 768              // kbuf: 64 rows * 12 dw
#define VTO 1536            // vbufT: 32 rows * 36 dw
#define PO 0                // pbuf overlays qbuf+kbuf (+ front of vbufT; Vf already in regs)
#define WS_NEED (8ull * HW * 72 * 2)   // y: (head, pixel, 72ch) f16 = 42.47 MB

typedef __fp16 h2  __attribute__((ext_vector_type(2)));
typedef __fp16 v8h __attribute__((ext_vector_type(8)));
typedef float  v4f __attribute__((ext_vector_type(4)));

static __device__ __forceinline__ h2 pk2(float a, float b) {
    return __builtin_amdgcn_cvt_pkrtz(a, b);
}
static __device__ __forceinline__ unsigned h2u(h2 x) {
    union { h2 h; unsigned u; } c; c.h = x; return c.u;
}
static __device__ __forceinline__ h2 u2h(unsigned x) {
    union { unsigned u; h2 h; } c; c.u = x; return c.h;
}
static __device__ __forceinline__ v8h as_v8h(uint4 u) {
    union { uint4 u; v8h h; } c; c.u = u; return c.h;
}

// ---- pre-pass: x (576,192,192) f32 -> y (8 heads, 36864 pixels, 36 dw of h2 pairs) ----
// y dword layout per pixel: [qkv*12 + dp]  (dp = d/2, pair (2dp, 2dp+1))
__global__ __launch_bounds__(256)
void transpose_x(const float* __restrict__ x, uint4* __restrict__ y4) {
    __shared__ unsigned tile[HDIM * 36];     // 27648 B
    const int head = blockIdx.x / HDIM;
    const int h    = blockIdx.x % HDIM;
    const int tid  = threadIdx.x;

#pragma unroll
    for (int qkv = 0; qkv < 3; ++qkv) {
        const float* xb = x + (size_t)(qkv * 192 + head * 24) * HW + h * HDIM;
#pragma unroll
        for (int it = 0; it < 9; ++it) {
            const int idx = it * 256 + tid;          // 0..2303
            const int dp  = idx / HDIM;
            const int w   = idx - dp * HDIM;
            const float a = xb[(size_t)(2 * dp)     * HW + w];
            const float b = xb[(size_t)(2 * dp + 1) * HW + w];
            tile[w * 36 + qkv * 12 + dp] = h2u(pk2(a, b));
        }
    }
    __syncthreads();
    const size_t pbase = (size_t)head * HW + (size_t)h * HDIM;
#pragma unroll
    for (int it = 0; it < 7; ++it) {
        const int gi = it * 256 + tid;               // 0..1727 (192 px * 9 uint4)
        if (gi < 1728) {
            const int p = gi / 9;
            const int j = gi - p * 9;
            y4[(pbase + p) * 9 + j] = *(const uint4*)&tile[p * 36 + 4 * j];
        }
    }
}

__global__ __launch_bounds__(128, 4)
void attn_mfma(const float* __restrict__ x,
               const uint4* __restrict__ y4,   // transposed f16 (or null -> direct path)
               const float* __restrict__ fc,
               const float* __restrict__ wgt,
               float* __restrict__ out)
{
    __shared__ unsigned lds[UPB * UDW];
    __shared__ float frs[64], fis[64];
    __shared__ unsigned zblk[4];

    const int wave = threadIdx.x >> 6;
    const int lane = threadIdx.x & 63;
    const int gid  = blockIdx.x * UPB + wave;
    const int head = gid & 7;
    const int wi   = gid >> 3;
    const int g    = wi & 3;
    const int iw   = (wi >> 2) & 15;
    const int ih   = wi >> 6;

    unsigned* uld = &lds[wave * UDW];

    if (threadIdx.x < 64) {
        float2 t = ((const float2*)fc)[threadIdx.x];
        frs[threadIdx.x] = t.x; fis[threadIdx.x] = t.y;
    } else if (threadIdx.x < 68) {
        zblk[threadIdx.x - 64] = 0;
    }

    // ---- phase 1: gather + PE + stage ----
    const int r = lane >> 3, col = lane & 7;
    const int h0 = ih * 12 + r, w0 = iw * 12 + col;
    int in_h = h0 + ((g & 1) ? 6 : 0); if (in_h >= HDIM) in_h = 2 * HDIM - 2 - in_h;
    int in_w = w0 + ((g & 2) ? 6 : 0); if (in_w >= HDIM) in_w = 2 * HDIM - 2 - in_w;

    float q[24], k[24], v[24];
    if (y4) {   // fast path: 9 contiguous uint4 loads (144 B/lane)
        const uint4* yb = y4 + ((size_t)head * HW + (size_t)in_h * HDIM + in_w) * 9;
        uint4 qa = yb[0], qb = yb[1], qc = yb[2];
        uint4 ka = yb[3], kb = yb[4], kc = yb[5];
        uint4 va = yb[6], vb = yb[7], vc = yb[8];
        const unsigned* qu = (const unsigned*)&qa;   // qa..qc contiguous? no — unpack separately
#pragma unroll
        for (int j = 0; j < 4; ++j) {
            h2 t;
            t = u2h(((const unsigned*)&qa)[j]); q[2*j]    = (float)t[0]; q[2*j+1]    = (float)t[1];
            t = u2h(((const unsigned*)&qb)[j]); q[8+2*j]  = (float)t[0]; q[8+2*j+1]  = (float)t[1];
            t = u2h(((const unsigned*)&qc)[j]); q[16+2*j] = (float)t[0]; q[16+2*j+1] = (float)t[1];
            t = u2h(((const unsigned*)&ka)[j]); k[2*j]    = (float)t[0]; k[2*j+1]    = (float)t[1];
            t = u2h(((const unsigned*)&kb)[j]); k[8+2*j]  = (float)t[0]; k[8+2*j+1]  = (float)t[1];
            t = u2h(((const unsigned*)&kc)[j]); k[16+2*j] = (float)t[0]; k[16+2*j+1] = (float)t[1];
            t = u2h(((const unsigned*)&va)[j]); v[2*j]    = (float)t[0]; v[2*j+1]    = (float)t[1];
            t = u2h(((const unsigned*)&vb)[j]); v[8+2*j]  = (float)t[0]; v[8+2*j+1]  = (float)t[1];
            t = u2h(((const unsigned*)&vc)[j]); v[16+2*j] = (float)t[0]; v[16+2*j+1] = (float)t[1];
        }
        (void)qu;
    } else {    // fallback: direct strided gather from x
        const float* xb = x + (size_t)(head * 24) * HW + in_h * HDIM + in_w;
#pragma unroll
        for (int dd = 0; dd < 24; ++dd) q[dd] = xb[(size_t)dd * HW];
#pragma unroll
        for (int dd = 0; dd < 24; ++dd) k[dd] = xb[(size_t)dd * HW + (size_t)192 * HW];
#pragma unroll
        for (int dd = 0; dd < 24; ++dd) v[dd] = xb[(size_t)dd * HW + (size_t)384 * HW];
    }

    __syncthreads();  // frs/fis/zblk ready

#pragma unroll
    for (int p = 0; p < 8; ++p) {
        const float frr = frs[r * 8 + p],   fir = fis[r * 8 + p];
        const float frc = frs[col * 8 + p], fic = fis[col * 8 + p];
        {
            float a = q[3*p], b = q[3*p+1], c3 = q[3*p+2];
            float b2 = a * fir + b * frr;
            q[3*p]   = a * frr - b * fir;
            q[3*p+1] = b2 * frc - c3 * fic;
            q[3*p+2] = b2 * fic + c3 * frc;
        }
        {
            float a = k[3*p], b = k[3*p+1], c3 = k[3*p+2];
            float b2 = a * fir + b * frr;
            k[3*p]   = a * frr - b * fir;
            k[3*p+1] = b2 * frc - c3 * fic;
            k[3*p+2] = b2 * fic + c3 * frc;
        }
    }

    {
        const float sc = 0.20412414523193154f;   // 1/sqrt(24)
        uint2* qw = (uint2*)&uld[QO + lane * 12];
        uint2* kw = (uint2*)&uld[KO + lane * 12];
#pragma unroll
        for (int j = 0; j < 3; ++j) {
            qw[2*j]   = make_uint2(h2u(pk2(q[8*j]*sc,   q[8*j+1]*sc)),
                                   h2u(pk2(q[8*j+2]*sc, q[8*j+3]*sc)));
            qw[2*j+1] = make_uint2(h2u(pk2(q[8*j+4]*sc, q[8*j+5]*sc)),
                                   h2u(pk2(q[8*j+6]*sc, q[8*j+7]*sc)));
            kw[2*j]   = make_uint2(h2u(pk2(k[8*j],   k[8*j+1])),
                                   h2u(pk2(k[8*j+2], k[8*j+3])));
            kw[2*j+1] = make_uint2(h2u(pk2(k[8*j+4], k[8*j+5])),
                                   h2u(pk2(k[8*j+6], k[8*j+7])));
        }
    }
    {
#pragma unroll
        for (int i = 0; i < 5; ++i) {           // zero V^T rows 24..31
            int idx = lane + i * 64;
            if (idx < 288) uld[VTO + 24 * 36 + idx] = 0;
        }
        __fp16* vt = (__fp16*)&uld[VTO];
        vt[24 * 72 + lane] = (__fp16)1.0f;      // ones row -> denominators
#pragma unroll
        for (int dd = 0; dd < 24; ++dd) vt[dd * 72 + lane] = (__fp16)v[dd];
    }
    __syncthreads();

    // ---- phase 2: fragments ----
    const int qq = lane >> 4, l15 = lane & 15;
    v8h Qf[4], Kf[4];
#pragma unroll
    for (int t = 0; t < 4; ++t) {
        const unsigned* qa = (qq < 3) ? &uld[QO + (16*t + l15)*12 + 4*qq] : zblk;
        const unsigned* ka = (qq < 3) ? &uld[KO + (16*t + l15)*12 + 4*qq] : zblk;
        Qf[t] = as_v8h(*(const uint4*)qa);
        Kf[t] = as_v8h(*(const uint4*)ka);
    }
    v8h Vf[2][2];
#pragma unroll
    for (int dt = 0; dt < 2; ++dt)
#pragma unroll
        for (int ks = 0; ks < 2; ++ks)
            Vf[dt][ks] = as_v8h(*(const uint4*)&uld[VTO + (16*dt + l15)*36 + 16*ks + 4*qq]);

    // ---- S = Q*K^T, exp, P -> LDS ----
    __fp16* pb = (__fp16*)&uld[PO];
#pragma unroll
    for (int tn = 0; tn < 4; ++tn) {
#pragma unroll
        for (int tm = 0; tm < 4; ++tm) {
            v4f c = {0.f, 0.f, 0.f, 0.f};
            c = __builtin_amdgcn_mfma_f32_16x16x32_f16(Qf[tm], Kf[tn], c, 0, 0, 0);
#pragma unroll
            for (int rg = 0; rg < 4; ++rg)
                pb[(16*tm + 4*qq + rg) * 72 + 16*tn + l15] = (__fp16)__expf(c[rg]);
        }
    }

    // ---- O^T = V^T * P^T ----
    v4f O[2][4];
#pragma unroll
    for (int dt = 0; dt < 2; ++dt)
#pragma unroll
        for (int lt = 0; lt < 4; ++lt)
            O[dt][lt] = (v4f){0.f, 0.f, 0.f, 0.f};
#pragma unroll
    for (int lt = 0; lt < 4; ++lt) {
#pragma unroll
        for (int ks = 0; ks < 2; ++ks) {
            v8h Pf = as_v8h(*(const uint4*)&uld[PO + (16*lt + l15)*36 + 16*ks + 4*qq]);
            O[0][lt] = __builtin_amdgcn_mfma_f32_16x16x32_f16(Vf[0][ks], Pf, O[0][lt], 0, 0, 0);
            O[1][lt] = __builtin_amdgcn_mfma_f32_16x16x32_f16(Vf[1][ks], Pf, O[1][lt], 0, 0, 0);
        }
    }

    float inv[4];
#pragma unroll
    for (int lt = 0; lt < 4; ++lt)
        inv[lt] = 1.0f / __shfl(O[1][lt][0], 32 + l15, 64);

    // ---- scatter ----
#pragma unroll
    for (int lt = 0; lt < 4; ++lt) {
        const int l  = 16*lt + l15;
        const int oh = ih * 12 + (l >> 3) + ((g & 1) ? 6 : 0);
        const int ow = iw * 12 + (l & 7)  + ((g & 2) ? 6 : 0);
        if (oh < HDIM && ow < HDIM) {
            const float sc = inv[lt] / wgt[oh * HDIM + ow];
            float* ob = out + (size_t)(head * 24) * HW + oh * HDIM + ow;
#pragma unroll
            for (int rg = 0; rg < 4; ++rg)
                atomicAdd(ob + (size_t)(4*qq + rg) * HW, O[0][lt][rg] * sc);
            if (qq < 2) {
#pragma unroll
                for (int rg = 0; rg < 4; ++rg)
                    atomicAdd(ob + (size_t)(16 + 4*qq + rg) * HW, O[1][lt][rg] * sc);
            }
        }
    }
}

extern "C" void kernel_launch(void* const* d_in, const int* in_sizes, int n_in,
                              void* d_out, int out_size, void* d_ws, size_t ws_size,
                              hipStream_t stream) {
    const float* x   = (const float*)d_in[0];
    const float* fc  = (const float*)d_in[1];
    const float* wgt = (const float*)d_in[2];
    float* out = (float*)d_out;

    (void)hipMemsetAsync(out, 0, (size_t)out_size * sizeof(float), stream);

    uint4* y4 = (ws_size >= WS_NEED) ? (uint4*)d_ws : nullptr;
    if (y4)
        transpose_x<<<8 * HDIM, 256, 0, stream>>>(x, y4);
    attn_mfma<<<NUNITS / UPB, UPB * 64, 0, stream>>>(x, y4, fc, wgt, out);
}

// Round 10
// 188.204 us; speedup vs baseline: 1.4043x; 1.4043x over previous
//
#include <hip/hip_runtime.h>

#define HW 36864            // 192*192
#define HDIM 192
#define NUNITS 8192         // 1024 windows * 8 heads
#define UPB 2               // units (waves) per block
#define UDW 2688            // LDS dwords per unit
#define QO 0
#define KO 768
#define VTO 1536
#define PO 0
#define O_BYTES (8192ull * 768 * 4)        // O workspace: unit * 12 h2-rows * 64 pos
#define Y_BYTES (8ull * HW * 72 * 2)       // transposed qkv, f16

typedef __fp16 h2  __attribute__((ext_vector_type(2)));
typedef __fp16 v8h __attribute__((ext_vector_type(8)));
typedef float  v4f __attribute__((ext_vector_type(4)));

static __device__ __forceinline__ h2 pk2(float a, float b) {
    return __builtin_amdgcn_cvt_pkrtz(a, b);
}
static __device__ __forceinline__ unsigned h2u(h2 x) {
    union { h2 h; unsigned u; } c; c.h = x; return c.u;
}
static __device__ __forceinline__ h2 u2h(unsigned x) {
    union { unsigned u; h2 h; } c; c.u = x; return c.h;
}
static __device__ __forceinline__ v8h as_v8h(uint4 u) {
    union { uint4 u; v8h h; } c; c.u = u; return c.h;
}

// ---- pre-pass: x (576,192,192) f32 -> y (head, pixel, 36 dw of h2 pairs), LDS-free ----
__global__ __launch_bounds__(256)
void transpose_x(const float* __restrict__ x, uint4* __restrict__ y4) {
    const int idx  = blockIdx.x * 256 + threadIdx.x;   // 0 .. 8*HW-1 (grid exact)
    const int head = idx / HW;
    const int pix  = idx - head * HW;
    const float* xp = x + (size_t)(head * 24) * HW + pix;

    unsigned o[36];
#pragma unroll
    for (int qkv = 0; qkv < 3; ++qkv)
#pragma unroll
        for (int dp = 0; dp < 12; ++dp) {
            const float a = xp[(size_t)(qkv * 192 + 2 * dp)     * HW];
            const float b = xp[(size_t)(qkv * 192 + 2 * dp + 1) * HW];
            o[qkv * 12 + dp] = h2u(pk2(a, b));
        }
    uint4* dst = y4 + (size_t)idx * 9;
#pragma unroll
    for (int j = 0; j < 9; ++j) dst[j] = *(const uint4*)&o[4 * j];
}

__global__ __launch_bounds__(128, 4)
void attn_mfma(const float* __restrict__ x,
               const uint4* __restrict__ y4,   // may be null -> direct gather
               const float* __restrict__ fc,
               const float* __restrict__ wgt,
               float* __restrict__ out,        // used only in atomic fallback
               unsigned* __restrict__ wsO)     // may be null -> atomic fallback
{
    __shared__ unsigned lds[UPB * UDW];
    __shared__ float frs[64], fis[64];
    __shared__ unsigned zblk[4];

    const int wave = threadIdx.x >> 6;
    const int lane = threadIdx.x & 63;
    const int gid  = blockIdx.x * UPB + wave;
    const int head = gid & 7;
    const int wi   = gid >> 3;
    const int g    = wi & 3;
    const int iw   = (wi >> 2) & 15;
    const int ih   = wi >> 6;

    unsigned* uld = &lds[wave * UDW];

    if (threadIdx.x < 64) {
        float2 t = ((const float2*)fc)[threadIdx.x];
        frs[threadIdx.x] = t.x; fis[threadIdx.x] = t.y;
    } else if (threadIdx.x < 68) {
        zblk[threadIdx.x - 64] = 0;
    }

    // ---- phase 1: gather + PE + stage ----
    const int r = lane >> 3, col = lane & 7;
    const int h0 = ih * 12 + r, w0 = iw * 12 + col;
    int in_h = h0 + ((g & 1) ? 6 : 0); if (in_h >= HDIM) in_h = 2 * HDIM - 2 - in_h;
    int in_w = w0 + ((g & 2) ? 6 : 0); if (in_w >= HDIM) in_w = 2 * HDIM - 2 - in_w;

    float q[24], k[24], v[24];
    if (y4) {
        const uint4* yb = y4 + ((size_t)head * HW + (size_t)in_h * HDIM + in_w) * 9;
        uint4 qa = yb[0], qb = yb[1], qc = yb[2];
        uint4 ka = yb[3], kb = yb[4], kc = yb[5];
        uint4 va = yb[6], vb = yb[7], vc = yb[8];
#pragma unroll
        for (int j = 0; j < 4; ++j) {
            h2 t;
            t = u2h(((const unsigned*)&qa)[j]); q[2*j]    = (float)t[0]; q[2*j+1]    = (float)t[1];
            t = u2h(((const unsigned*)&qb)[j]); q[8+2*j]  = (float)t[0]; q[8+2*j+1]  = (float)t[1];
            t = u2h(((const unsigned*)&qc)[j]); q[16+2*j] = (float)t[0]; q[16+2*j+1] = (float)t[1];
            t = u2h(((const unsigned*)&ka)[j]); k[2*j]    = (float)t[0]; k[2*j+1]    = (float)t[1];
            t = u2h(((const unsigned*)&kb)[j]); k[8+2*j]  = (float)t[0]; k[8+2*j+1]  = (float)t[1];
            t = u2h(((const unsigned*)&kc)[j]); k[16+2*j] = (float)t[0]; k[16+2*j+1] = (float)t[1];
            t = u2h(((const unsigned*)&va)[j]); v[2*j]    = (float)t[0]; v[2*j+1]    = (float)t[1];
            t = u2h(((const unsigned*)&vb)[j]); v[8+2*j]  = (float)t[0]; v[8+2*j+1]  = (float)t[1];
            t = u2h(((const unsigned*)&vc)[j]); v[16+2*j] = (float)t[0]; v[16+2*j+1] = (float)t[1];
        }
    } else {
        const float* xb = x + (size_t)(head * 24) * HW + in_h * HDIM + in_w;
#pragma unroll
        for (int dd = 0; dd < 24; ++dd) q[dd] = xb[(size_t)dd * HW];
#pragma unroll
        for (int dd = 0; dd < 24; ++dd) k[dd] = xb[(size_t)dd * HW + (size_t)192 * HW];
#pragma unroll
        for (int dd = 0; dd < 24; ++dd) v[dd] = xb[(size_t)dd * HW + (size_t)384 * HW];
    }

    __syncthreads();

#pragma unroll
    for (int p = 0; p < 8; ++p) {
        const float frr = frs[r * 8 + p],   fir = fis[r * 8 + p];
        const float frc = frs[col * 8 + p], fic = fis[col * 8 + p];
        {
            float a = q[3*p], b = q[3*p+1], c3 = q[3*p+2];
            float b2 = a * fir + b * frr;
            q[3*p]   = a * frr - b * fir;
            q[3*p+1] = b2 * frc - c3 * fic;
            q[3*p+2] = b2 * fic + c3 * frc;
        }
        {
            float a = k[3*p], b = k[3*p+1], c3 = k[3*p+2];
            float b2 = a * fir + b * frr;
            k[3*p]   = a * frr - b * fir;
            k[3*p+1] = b2 * frc - c3 * fic;
            k[3*p+2] = b2 * fic + c3 * frc;
        }
    }

    {
        const float sc = 0.20412414523193154f;   // 1/sqrt(24)
        uint2* qw = (uint2*)&uld[QO + lane * 12];
        uint2* kw = (uint2*)&uld[KO + lane * 12];
#pragma unroll
        for (int j = 0; j < 3; ++j) {
            qw[2*j]   = make_uint2(h2u(pk2(q[8*j]*sc,   q[8*j+1]*sc)),
                                   h2u(pk2(q[8*j+2]*sc, q[8*j+3]*sc)));
            qw[2*j+1] = make_uint2(h2u(pk2(q[8*j+4]*sc, q[8*j+5]*sc)),
                                   h2u(pk2(q[8*j+6]*sc, q[8*j+7]*sc)));
            kw[2*j]   = make_uint2(h2u(pk2(k[8*j],   k[8*j+1])),
                                   h2u(pk2(k[8*j+2], k[8*j+3])));
            kw[2*j+1] = make_uint2(h2u(pk2(k[8*j+4], k[8*j+5])),
                                   h2u(pk2(k[8*j+6], k[8*j+7])));
        }
    }
    {
#pragma unroll
        for (int i = 0; i < 5; ++i) {           // zero V^T rows 24..31
            int idx = lane + i * 64;
            if (idx < 288) uld[VTO + 24 * 36 + idx] = 0;
        }
        __fp16* vt = (__fp16*)&uld[VTO];
        vt[24 * 72 + lane] = (__fp16)1.0f;      // ones row -> denominators
#pragma unroll
        for (int dd = 0; dd < 24; ++dd) vt[dd * 72 + lane] = (__fp16)v[dd];
    }
    __syncthreads();

    // ---- phase 2 ----
    const int qq = lane >> 4, l15 = lane & 15;
    v8h Qf[4], Kf[4];
#pragma unroll
    for (int t = 0; t < 4; ++t) {
        const unsigned* qa = (qq < 3) ? &uld[QO + (16*t + l15)*12 + 4*qq] : zblk;
        const unsigned* ka = (qq < 3) ? &uld[KO + (16*t + l15)*12 + 4*qq] : zblk;
        Qf[t] = as_v8h(*(const uint4*)qa);
        Kf[t] = as_v8h(*(const uint4*)ka);
    }
    v8h Vf[2][2];
#pragma unroll
    for (int dt = 0; dt < 2; ++dt)
#pragma unroll
        for (int ks = 0; ks < 2; ++ks)
            Vf[dt][ks] = as_v8h(*(const uint4*)&uld[VTO + (16*dt + l15)*36 + 16*ks + 4*qq]);

    __fp16* pb = (__fp16*)&uld[PO];
#pragma unroll
    for (int tn = 0; tn < 4; ++tn) {
#pragma unroll
        for (int tm = 0; tm < 4; ++tm) {
            v4f c = {0.f, 0.f, 0.f, 0.f};
            c = __builtin_amdgcn_mfma_f32_16x16x32_f16(Qf[tm], Kf[tn], c, 0, 0, 0);
#pragma unroll
            for (int rg = 0; rg < 4; ++rg)
                pb[(16*tm + 4*qq + rg) * 72 + 16*tn + l15] = (__fp16)__expf(c[rg]);
        }
    }

    v4f O[2][4];
#pragma unroll
    for (int dt = 0; dt < 2; ++dt)
#pragma unroll
        for (int lt = 0; lt < 4; ++lt)
            O[dt][lt] = (v4f){0.f, 0.f, 0.f, 0.f};
#pragma unroll
    for (int lt = 0; lt < 4; ++lt) {
#pragma unroll
        for (int ks = 0; ks < 2; ++ks) {
            v8h Pf = as_v8h(*(const uint4*)&uld[PO + (16*lt + l15)*36 + 16*ks + 4*qq]);
            O[0][lt] = __builtin_amdgcn_mfma_f32_16x16x32_f16(Vf[0][ks], Pf, O[0][lt], 0, 0, 0);
            O[1][lt] = __builtin_amdgcn_mfma_f32_16x16x32_f16(Vf[1][ks], Pf, O[1][lt], 0, 0, 0);
        }
    }

    float inv[4];
#pragma unroll
    for (int lt = 0; lt < 4; ++lt)
        inv[lt] = 1.0f / __shfl(O[1][lt][0], 32 + l15, 64);

    if (wsO) {
        // non-atomic epilogue: O*(1/sum) as f16 pairs -> ws[unit][dp][pos]
        unsigned* wb = wsO + (size_t)gid * 768;
#pragma unroll
        for (int lt = 0; lt < 4; ++lt) {
            const int   l  = 16*lt + l15;
            const float sc = inv[lt];
            wb[(2*qq+0) * 64 + l] = h2u(pk2(O[0][lt][0]*sc, O[0][lt][1]*sc));
            wb[(2*qq+1) * 64 + l] = h2u(pk2(O[0][lt][2]*sc, O[0][lt][3]*sc));
            if (qq < 2) {
                wb[(8+2*qq)   * 64 + l] = h2u(pk2(O[1][lt][0]*sc, O[1][lt][1]*sc));
                wb[(8+2*qq+1) * 64 + l] = h2u(pk2(O[1][lt][2]*sc, O[1][lt][3]*sc));
            }
        }
    } else {
        // atomic fallback
#pragma unroll
        for (int lt = 0; lt < 4; ++lt) {
            const int l  = 16*lt + l15;
            const int oh = ih * 12 + (l >> 3) + ((g & 1) ? 6 : 0);
            const int ow = iw * 12 + (l & 7)  + ((g & 2) ? 6 : 0);
            if (oh < HDIM && ow < HDIM) {
                const float sc = inv[lt] / wgt[oh * HDIM + ow];
                float* ob = out + (size_t)(head * 24) * HW + oh * HDIM + ow;
#pragma unroll
                for (int rg = 0; rg < 4; ++rg)
                    atomicAdd(ob + (size_t)(4*qq + rg) * HW, O[0][lt][rg] * sc);
                if (qq < 2) {
#pragma unroll
                    for (int rg = 0; rg < 4; ++rg)
                        atomicAdd(ob + (size_t)(16 + 4*qq + rg) * HW, O[1][lt][rg] * sc);
                }
            }
        }
    }
}

// ---- phase B: overlap-add merge; out has 192 channels (8 heads * 24 dims) ----
__global__ __launch_bounds__(256)
void merge_out(const unsigned* __restrict__ wsO,
               const float* __restrict__ wgt,
               float* __restrict__ out)
{
    const int idx = blockIdx.x * 256 + threadIdx.x;    // grid exact: 192*HW
    const int c   = idx / HW;                          // 0..191
    const int pix = idx - c * HW;
    const int h   = pix / HDIM;
    const int w   = pix - h * HDIM;
    const int head = c / 24;                           // 0..7
    const int d    = c - head * 24;
    const int dp = d >> 1, hi = d & 1;

    float acc = 0.f;
#pragma unroll
    for (int g = 0; g < 4; ++g) {
        const int hh = h - ((g & 1) ? 6 : 0);
        const int ww = w - ((g & 2) ? 6 : 0);
        if (hh < 0 || ww < 0) continue;
        const int ih = hh / 12, r  = hh - ih * 12;
        const int iw = ww / 12, cw = ww - iw * 12;
        if (r >= 8 || cw >= 8) continue;
        const int unit = ((ih * 16 + iw) * 4 + g) * 8 + head;
        const unsigned u = wsO[(size_t)unit * 768 + dp * 64 + r * 8 + cw];
        acc += (float)u2h(u)[hi];
    }
    out[idx] = acc / wgt[pix];
}

extern "C" void kernel_launch(void* const* d_in, const int* in_sizes, int n_in,
                              void* d_out, int out_size, void* d_ws, size_t ws_size,
                              hipStream_t stream) {
    const float* x   = (const float*)d_in[0];
    const float* fc  = (const float*)d_in[1];
    const float* wgt = (const float*)d_in[2];
    float* out = (float*)d_out;

    const bool full  = ws_size >= O_BYTES + Y_BYTES;
    const bool ypath = full || ws_size >= Y_BYTES;
    unsigned* wsO = full ? (unsigned*)d_ws : nullptr;
    uint4*    y4  = full ? (uint4*)((char*)d_ws + O_BYTES)
                         : (ypath ? (uint4*)d_ws : nullptr);

    if (!full)
        (void)hipMemsetAsync(out, 0, (size_t)out_size * sizeof(float), stream);
    if (ypath)
        transpose_x<<<8 * HW / 256, 256, 0, stream>>>(x, y4);
    attn_mfma<<<NUNITS / UPB, UPB * 64, 0, stream>>>(x, y4, fc, wgt, out, wsO);
    if (full)
        merge_out<<<192 * HW / 256, 256, 0, stream>>>(wsO, wgt, out);
}